// Round 2
// baseline (32.328 us; speedup 1.0000x reference)
//
#include <hip/hip_runtime.h>

// LBP encoder: out[n,k,h,w] = sigmoid(img[n,0,clamp(h+dy_k),clamp(w+dx_k)] - img[n,0,h,w])
// Offsets k=0..7: (-1,-1),(-1,0),(-1,1),(0,-1),(0,1),(1,-1),(1,0),(1,1)
// Key identity: offset pairs (k, 7-k) are antipodal -> out_{7-k}(p+o_k) = 1 - out_k(p).
// Each thread owns an 8x4 tile; per "edge" we compute ONE sigmoid and write two outputs.
// All stores are aligned float4; border elements are recomputed in-lane from the halo
// so every output location has exactly one writer (no cleanup pass, no races).

#define NH 512
#define NW 512
#define HWSZ (NH * NW)

__device__ __forceinline__ float fexp2(float x) {
#if __has_builtin(__builtin_amdgcn_exp2f)
    return __builtin_amdgcn_exp2f(x);
#else
    return __expf(x * 0.6931471805599453f);
#endif
}

// Inputs pre-scaled by log2(e): returns sigmoid(nb - c) = 1 / (1 + 2^(cL - nbL))
__device__ __forceinline__ float sigm(float nbL, float cL) {
    return __builtin_amdgcn_rcpf(1.0f + fexp2(cL - nbL));
}

__global__ __launch_bounds__(256) void lbp_main(const float* __restrict__ img,
                                                float* __restrict__ out) {
    const float L2E = 1.4426950408889634f;
    int t = blockIdx.x * 256 + threadIdx.x;
    int lane = t & 63;            // 64 lanes x 8 cols = full 512-col row
    int w0 = lane << 3;
    int strip = (t >> 6) & 127;   // 128 strips of 4 rows
    int h0 = strip << 2;
    int n = t >> 13;              // 16 images

    const float* src = img + (size_t)n * HWSZ;

    // Halo window: rows h0-1..h0+3 (top clamped), cols w0-1..w0+8 (clamped),
    // pre-scaled by log2(e) so each sigmoid is sub+exp+add+rcp only.
    float v[5][10];
    int wl = max(w0 - 1, 0);
    int wr = min(w0 + 8, NW - 1);
#pragma unroll
    for (int r = 0; r < 5; ++r) {
        int row = max(h0 - 1 + r, 0);   // h0+3 <= 511 always
        const float* rp = src + row * NW;
        float4 a = *reinterpret_cast<const float4*>(rp + w0);
        float4 b = *reinterpret_cast<const float4*>(rp + w0 + 4);
        v[r][0] = rp[wl] * L2E;
        v[r][1] = a.x * L2E; v[r][2] = a.y * L2E; v[r][3] = a.z * L2E; v[r][4] = a.w * L2E;
        v[r][5] = b.x * L2E; v[r][6] = b.y * L2E; v[r][7] = b.z * L2E; v[r][8] = b.w * L2E;
        v[r][9] = rp[wr] * L2E;
    }

    float* ob = out + (size_t)n * 8 * HWSZ;

#pragma unroll
    for (int k = 0; k < 4; ++k) {
        const int dy = (k < 3) ? -1 : 0;
        const int dx = (k == 0) ? -1 : (k == 1) ? 0 : (k == 2) ? 1 : -1;
        float* odir = ob + (size_t)k * HWSZ;
        float* oder = ob + (size_t)(7 - k) * HWSZ;
#pragma unroll
        for (int r = 0; r < 4; ++r) {
            // Direct outputs for class k at row h0+r (clamped neighbor via halo).
            float s[8];
#pragma unroll
            for (int i = 0; i < 8; ++i)
                s[i] = sigm(v[r + 1 + dy][i + 1 + dx], v[r + 1][i + 1]);

            *reinterpret_cast<float4*>(odir + (h0 + r) * NW + w0) =
                make_float4(s[0], s[1], s[2], s[3]);
            *reinterpret_cast<float4*>(odir + (h0 + r) * NW + w0 + 4) =
                make_float4(s[4], s[5], s[6], s[7]);

            // Derived channel 7-k at row h0+r+dy, cols w0..w0+7 (aligned).
            // Interior elements are 1-s shifted by dx; the one boundary element
            // per row is computed directly from the halo (also correct at the
            // image edge because the halo is clamp-loaded).
            float vr8[8];
            if (dx == -1) {
#pragma unroll
                for (int j = 0; j < 7; ++j) vr8[j] = 1.0f - s[j + 1];
                vr8[7] = sigm(v[r + 1][9], v[r + 1 + dy][8]);
            } else if (dx == 1) {
                vr8[0] = sigm(v[r + 1][0], v[r][1]);
#pragma unroll
                for (int j = 1; j < 8; ++j) vr8[j] = 1.0f - s[j - 1];
            } else {
#pragma unroll
                for (int j = 0; j < 8; ++j) vr8[j] = 1.0f - s[j];
            }

            int qrow = h0 + r + dy;
            if (r > 0 || dy == 0 || h0 > 0) {   // skip only q-row -1 (wave-uniform)
                *reinterpret_cast<float4*>(oder + qrow * NW + w0) =
                    make_float4(vr8[0], vr8[1], vr8[2], vr8[3]);
                *reinterpret_cast<float4*>(oder + qrow * NW + w0 + 4) =
                    make_float4(vr8[4], vr8[5], vr8[6], vr8[7]);
            }
        }
    }

    // Bottom strip supplies the last row (H-1) of the derived channels 5,6,7.
    if (h0 == NH - 4) {
        float e5[8], e7[8];
#pragma unroll
        for (int i = 0; i < 8; ++i) {
            e7[i] = sigm(v[4][i + 2], v[4][i + 1]);  // out7(H-1,w)=sig(img(H-1,min(w+1))-img)
            e5[i] = sigm(v[4][i], v[4][i + 1]);      // out5(H-1,w)=sig(img(H-1,max(w-1))-img)
        }
        float* o5 = ob + (size_t)5 * HWSZ + (NH - 1) * NW + w0;
        float* o6 = ob + (size_t)6 * HWSZ + (NH - 1) * NW + w0;
        float* o7 = ob + (size_t)7 * HWSZ + (NH - 1) * NW + w0;
        *reinterpret_cast<float4*>(o5)     = make_float4(e5[0], e5[1], e5[2], e5[3]);
        *reinterpret_cast<float4*>(o5 + 4) = make_float4(e5[4], e5[5], e5[6], e5[7]);
        *reinterpret_cast<float4*>(o6)     = make_float4(0.5f, 0.5f, 0.5f, 0.5f);
        *reinterpret_cast<float4*>(o6 + 4) = make_float4(0.5f, 0.5f, 0.5f, 0.5f);
        *reinterpret_cast<float4*>(o7)     = make_float4(e7[0], e7[1], e7[2], e7[3]);
        *reinterpret_cast<float4*>(o7 + 4) = make_float4(e7[4], e7[5], e7[6], e7[7]);
    }
}

extern "C" void kernel_launch(void* const* d_in, const int* in_sizes, int n_in,
                              void* d_out, int out_size, void* d_ws, size_t ws_size,
                              hipStream_t stream) {
    const float* img = (const float*)d_in[0];
    float* out = (float*)d_out;
    // threads = 16 images * 128 strips * 64 lanes = 131072 -> 512 blocks x 256
    lbp_main<<<512, 256, 0, stream>>>(img, out);
}

// Round 3
// 30.092 us; speedup vs baseline: 1.0743x; 1.0743x over previous
//
#include <hip/hip_runtime.h>

// LBP encoder: out[n,k,h,w] = sigmoid(img[n,0,clamp(h+dy_k),clamp(w+dx_k)] - img[n,0,h,w])
// Offsets k=0..7: (-1,-1),(-1,0),(-1,1),(0,-1),(0,1),(1,-1),(1,0),(1,1)
// Round 3: issue-minimized, fully-coalesced variant.
//  - thread = 4 consecutive pixels; lane stride 16B -> every store instruction
//    writes 1KB dense (8 full 128B lines).
//  - sigmoid = sub + v_exp_f32 + add + v_rcp_f32 (inputs pre-scaled by log2 e);
//    no IEEE div sequence.
//  - n is derived from blockIdx only -> all 8 channel bases are wave-uniform
//    (SGPR saddr stores, single shared voffset VGPR).
//  - 4096 blocks x 256 -> 16 blocks/CU, full wave occupancy.

#define NH 512
#define NW 512
#define HWSZ (NH * NW)

__device__ __forceinline__ float fexp2(float x) {
#if __has_builtin(__builtin_amdgcn_exp2f)
    return __builtin_amdgcn_exp2f(x);
#else
    return __expf(x * 0.6931471805599453f);
#endif
}

__device__ __forceinline__ float frcp(float x) {
#if __has_builtin(__builtin_amdgcn_rcpf)
    return __builtin_amdgcn_rcpf(x);
#else
    return 1.0f / x;
#endif
}

__global__ __launch_bounds__(256) void lbp_kernel(const float* __restrict__ img,
                                                  float* __restrict__ out) {
    const float L2E = 1.4426950408889634f;

    // 256 blocks per image; n provably uniform from blockIdx.
    int n = blockIdx.x >> 8;
    int local = ((blockIdx.x & 255) << 8) | threadIdx.x;  // 0..65535 within image
    int w0 = (local & 127) << 2;                          // 128 groups of 4 cols
    int h  = local >> 7;                                  // 0..511

    const float* src = img + (size_t)n * HWSZ;
    int rowm = (h > 0 ? h - 1 : 0) * NW;
    int rowc = h * NW;
    int rowp = (h < NH - 1 ? h + 1 : NH - 1) * NW;
    int wl = (w0 > 0) ? w0 - 1 : 0;
    int wr = (w0 + 4 < NW) ? w0 + 4 : NW - 1;

    // Halo rows (pre-scaled by log2 e): cols w0-1 .. w0+4, edge-replicated.
    float r[3][6];
    int rows[3] = {rowm, rowc, rowp};
#pragma unroll
    for (int i = 0; i < 3; ++i) {
        const float* rp = src + rows[i];
        float4 m = *reinterpret_cast<const float4*>(rp + w0);
        r[i][0] = rp[wl] * L2E;
        r[i][1] = m.x * L2E;
        r[i][2] = m.y * L2E;
        r[i][3] = m.z * L2E;
        r[i][4] = m.w * L2E;
        r[i][5] = rp[wr] * L2E;
    }

    int off = rowc + w0;  // shared store offset (elements)

    // Row index into r[] and column base (dx+1) for each of the 8 offsets.
    const int RI[8] = {0, 0, 0, 1, 1, 2, 2, 2};
    const int CI[8] = {0, 1, 2, 0, 2, 0, 1, 2};

#pragma unroll
    for (int k = 0; k < 8; ++k) {
        const int ri = RI[k], ci = CI[k];
        float4 res;
#pragma unroll
        for (int i = 0; i < 4; ++i) {
            // sigmoid(nb - c) = 1 / (1 + 2^(cL - nbL))
            float s = frcp(1.0f + fexp2(r[1][i + 1] - r[ri][i + ci]));
            (&res.x)[i] = s;
        }
        float* base = out + ((size_t)(n * 8 + k)) * HWSZ;  // wave-uniform -> SGPR
        *reinterpret_cast<float4*>(base + off) = res;
    }
}

extern "C" void kernel_launch(void* const* d_in, const int* in_sizes, int n_in,
                              void* d_out, int out_size, void* d_ws, size_t ws_size,
                              hipStream_t stream) {
    const float* img = (const float*)d_in[0];
    float* out = (float*)d_out;
    // 16 images * 256 blocks/image = 4096 blocks of 256 threads
    lbp_kernel<<<4096, 256, 0, stream>>>(img, out);
}

// Round 5
// 29.361 us; speedup vs baseline: 1.1010x; 1.0249x over previous
//
#include <hip/hip_runtime.h>

// LBP encoder: out[n,k,h,w] = sigmoid(img[n,0,clamp(h+dy_k),clamp(w+dx_k)] - img[n,0,h,w])
// Offsets k=0..7: (-1,-1),(-1,0),(-1,1),(0,-1),(0,1),(1,-1),(1,0),(1,1)
// Round 5: round-3 structure + NON-TEMPORAL stores via native ext_vector type
// (__builtin_nontemporal_store rejects HIP_vector_type float4).
//  - output is write-once/never-read: nt stores bypass L2/L3 allocation.
//  - input loads remain cached (each input byte reused ~9x).

#define NH 512
#define NW 512
#define HWSZ (NH * NW)

typedef float fx4 __attribute__((ext_vector_type(4)));

__device__ __forceinline__ float fexp2(float x) {
#if __has_builtin(__builtin_amdgcn_exp2f)
    return __builtin_amdgcn_exp2f(x);
#else
    return __expf(x * 0.6931471805599453f);
#endif
}

__device__ __forceinline__ float frcp(float x) {
#if __has_builtin(__builtin_amdgcn_rcpf)
    return __builtin_amdgcn_rcpf(x);
#else
    return 1.0f / x;
#endif
}

__global__ __launch_bounds__(256) void lbp_kernel(const float* __restrict__ img,
                                                  float* __restrict__ out) {
    const float L2E = 1.4426950408889634f;

    // 256 blocks per image; n provably uniform from blockIdx.
    int n = blockIdx.x >> 8;
    int local = ((blockIdx.x & 255) << 8) | threadIdx.x;  // 0..65535 within image
    int w0 = (local & 127) << 2;                          // 128 groups of 4 cols
    int h  = local >> 7;                                  // 0..511

    const float* src = img + (size_t)n * HWSZ;
    int rowm = (h > 0 ? h - 1 : 0) * NW;
    int rowc = h * NW;
    int rowp = (h < NH - 1 ? h + 1 : NH - 1) * NW;
    int wl = (w0 > 0) ? w0 - 1 : 0;
    int wr = (w0 + 4 < NW) ? w0 + 4 : NW - 1;

    // Halo rows (pre-scaled by log2 e): cols w0-1 .. w0+4, edge-replicated.
    float r[3][6];
    int rows[3] = {rowm, rowc, rowp};
#pragma unroll
    for (int i = 0; i < 3; ++i) {
        const float* rp = src + rows[i];
        fx4 m = *reinterpret_cast<const fx4*>(rp + w0);
        r[i][0] = rp[wl] * L2E;
        r[i][1] = m.x * L2E;
        r[i][2] = m.y * L2E;
        r[i][3] = m.z * L2E;
        r[i][4] = m.w * L2E;
        r[i][5] = rp[wr] * L2E;
    }

    int off = rowc + w0;  // shared store offset (elements)

    // Row index into r[] and column base (dx+1) for each of the 8 offsets.
    const int RI[8] = {0, 0, 0, 1, 1, 2, 2, 2};
    const int CI[8] = {0, 1, 2, 0, 2, 0, 1, 2};

#pragma unroll
    for (int k = 0; k < 8; ++k) {
        const int ri = RI[k], ci = CI[k];
        fx4 res;
#pragma unroll
        for (int i = 0; i < 4; ++i) {
            // sigmoid(nb - c) = 1 / (1 + 2^(cL - nbL))
            res[i] = frcp(1.0f + fexp2(r[1][i + 1] - r[ri][i + ci]));
        }
        float* base = out + ((size_t)(n * 8 + k)) * HWSZ;  // wave-uniform -> SGPR
        __builtin_nontemporal_store(res, reinterpret_cast<fx4*>(base + off));
    }
}

extern "C" void kernel_launch(void* const* d_in, const int* in_sizes, int n_in,
                              void* d_out, int out_size, void* d_ws, size_t ws_size,
                              hipStream_t stream) {
    const float* img = (const float*)d_in[0];
    float* out = (float*)d_out;
    // 16 images * 256 blocks/image = 4096 blocks of 256 threads
    lbp_kernel<<<4096, 256, 0, stream>>>(img, out);
}

// Round 6
// 28.751 us; speedup vs baseline: 1.1244x; 1.0212x over previous
//
#include <hip/hip_runtime.h>

// LBP encoder: out[n,k,h,w] = sigmoid(img[n,0,clamp(h+dy_k),clamp(w+dx_k)] - img[n,0,h,w])
// Offsets k=0..7: (-1,-1),(-1,0),(-1,1),(0,-1),(0,1),(1,-1),(1,0),(1,1)
// Round 6: 4-col x 2-row tile per thread + nt stores.
//  - halves wave count, halo loads per output byte, and address setup;
//  - each wave writes two consecutive dense 1KB chunks per channel plane;
//  - stores remain nt (write-once output, bypass cache allocation).

#define NH 512
#define NW 512
#define HWSZ (NH * NW)

typedef float fx4 __attribute__((ext_vector_type(4)));

__device__ __forceinline__ float fexp2(float x) {
#if __has_builtin(__builtin_amdgcn_exp2f)
    return __builtin_amdgcn_exp2f(x);
#else
    return __expf(x * 0.6931471805599453f);
#endif
}

__device__ __forceinline__ float frcp(float x) {
#if __has_builtin(__builtin_amdgcn_rcpf)
    return __builtin_amdgcn_rcpf(x);
#else
    return 1.0f / x;
#endif
}

__global__ __launch_bounds__(256) void lbp_kernel(const float* __restrict__ img,
                                                  float* __restrict__ out) {
    const float L2E = 1.4426950408889634f;

    // 128 blocks per image; n provably uniform from blockIdx.
    int n = blockIdx.x >> 7;
    int local = ((blockIdx.x & 127) << 8) | threadIdx.x;  // 0..32767 within image
    int w0 = (local & 127) << 2;                          // 128 groups of 4 cols
    int h0 = (local >> 7) << 1;                           // 256 strips of 2 rows

    const float* src = img + (size_t)n * HWSZ;
    int wl = (w0 > 0) ? w0 - 1 : 0;
    int wr = (w0 + 4 < NW) ? w0 + 4 : NW - 1;

    // Halo: rows h0-1 .. h0+2 (clamped), cols w0-1 .. w0+4 (clamped),
    // pre-scaled by log2(e) so sigmoid = sub + exp2 + add + rcp.
    float r[4][6];
#pragma unroll
    for (int i = 0; i < 4; ++i) {
        int row = h0 - 1 + i;
        row = (row < 0) ? 0 : ((row > NH - 1) ? NH - 1 : row);
        const float* rp = src + row * NW;
        fx4 m = *reinterpret_cast<const fx4*>(rp + w0);
        r[i][0] = rp[wl] * L2E;
        r[i][1] = m.x * L2E;
        r[i][2] = m.y * L2E;
        r[i][3] = m.z * L2E;
        r[i][4] = m.w * L2E;
        r[i][5] = rp[wr] * L2E;
    }

    int off = h0 * NW + w0;  // shared store offset (elements)

    // Row delta and column base (dx+1) for each of the 8 offsets.
    const int RI[8] = {0, 0, 0, 1, 1, 2, 2, 2};  // dy+1
    const int CI[8] = {0, 1, 2, 0, 2, 0, 1, 2};  // dx+1

#pragma unroll
    for (int k = 0; k < 8; ++k) {
        const int ri = RI[k], ci = CI[k];
        float* base = out + ((size_t)(n * 8 + k)) * HWSZ;  // wave-uniform -> SGPR
#pragma unroll
        for (int rr = 0; rr < 2; ++rr) {
            fx4 res;
#pragma unroll
            for (int i = 0; i < 4; ++i) {
                // sigmoid(nb - c) = 1 / (1 + 2^(cL - nbL))
                res[i] = frcp(1.0f + fexp2(r[rr + 1][i + 1] - r[rr + ri][i + ci]));
            }
            __builtin_nontemporal_store(res, reinterpret_cast<fx4*>(base + off + rr * NW));
        }
    }
}

extern "C" void kernel_launch(void* const* d_in, const int* in_sizes, int n_in,
                              void* d_out, int out_size, void* d_ws, size_t ws_size,
                              hipStream_t stream) {
    const float* img = (const float*)d_in[0];
    float* out = (float*)d_out;
    // 16 images * 128 blocks/image = 2048 blocks of 256 threads
    lbp_kernel<<<2048, 256, 0, stream>>>(img, out);
}

// Round 7
// 26.826 us; speedup vs baseline: 1.2051x; 1.0718x over previous
//
#include <hip/hip_runtime.h>

// LBP encoder: out[n,k,h,w] = sigmoid(img[n,0,clamp(h+dy_k),clamp(w+dx_k)] - img[n,0,h,w])
// Offsets k=0..7: (-1,-1),(-1,0),(-1,1),(0,-1),(0,1),(1,-1),(1,0),(1,1)
// Round 7: round-6 kernel + XCD-chunked block swizzle (single-variable change).
//  - default dispatch round-robins blocks across 8 XCDs -> vertically adjacent
//    bands (which share halo rows) land on different, non-coherent L2s.
//  - swizzle wgid = (bid&7)*256 + (bid>>3): each XCD gets 256 consecutive
//    work-ids = 4 whole images (4 MiB input), processed band-sequentially ->
//    halo re-reads hit that XCD's L2. nt stores keep the output out of L2.

#define NH 512
#define NW 512
#define HWSZ (NH * NW)

typedef float fx4 __attribute__((ext_vector_type(4)));

__device__ __forceinline__ float fexp2(float x) {
#if __has_builtin(__builtin_amdgcn_exp2f)
    return __builtin_amdgcn_exp2f(x);
#else
    return __expf(x * 0.6931471805599453f);
#endif
}

__device__ __forceinline__ float frcp(float x) {
#if __has_builtin(__builtin_amdgcn_rcpf)
    return __builtin_amdgcn_rcpf(x);
#else
    return 1.0f / x;
#endif
}

__global__ __launch_bounds__(256) void lbp_kernel(const float* __restrict__ img,
                                                  float* __restrict__ out) {
    const float L2E = 1.4426950408889634f;

    // XCD-chunked swizzle: 2048 blocks, 8 XCDs, 256 blocks/XCD chunk.
    int bid = blockIdx.x;
    int wgid = ((bid & 7) << 8) + (bid >> 3);

    // 128 work-ids per image; n provably uniform per wave.
    int n = wgid >> 7;
    int local = ((wgid & 127) << 8) | threadIdx.x;  // 0..32767 within image
    int w0 = (local & 127) << 2;                    // 128 groups of 4 cols
    int h0 = (local >> 7) << 1;                     // 256 strips of 2 rows

    const float* src = img + (size_t)n * HWSZ;
    int wl = (w0 > 0) ? w0 - 1 : 0;
    int wr = (w0 + 4 < NW) ? w0 + 4 : NW - 1;

    // Halo: rows h0-1 .. h0+2 (clamped), cols w0-1 .. w0+4 (clamped),
    // pre-scaled by log2(e) so sigmoid = sub + exp2 + add + rcp.
    float r[4][6];
#pragma unroll
    for (int i = 0; i < 4; ++i) {
        int row = h0 - 1 + i;
        row = (row < 0) ? 0 : ((row > NH - 1) ? NH - 1 : row);
        const float* rp = src + row * NW;
        fx4 m = *reinterpret_cast<const fx4*>(rp + w0);
        r[i][0] = rp[wl] * L2E;
        r[i][1] = m.x * L2E;
        r[i][2] = m.y * L2E;
        r[i][3] = m.z * L2E;
        r[i][4] = m.w * L2E;
        r[i][5] = rp[wr] * L2E;
    }

    int off = h0 * NW + w0;  // shared store offset (elements)

    // Row delta and column base (dx+1) for each of the 8 offsets.
    const int RI[8] = {0, 0, 0, 1, 1, 2, 2, 2};  // dy+1
    const int CI[8] = {0, 1, 2, 0, 2, 0, 1, 2};  // dx+1

#pragma unroll
    for (int k = 0; k < 8; ++k) {
        const int ri = RI[k], ci = CI[k];
        float* base = out + ((size_t)(n * 8 + k)) * HWSZ;  // wave-uniform -> SGPR
#pragma unroll
        for (int rr = 0; rr < 2; ++rr) {
            fx4 res;
#pragma unroll
            for (int i = 0; i < 4; ++i) {
                // sigmoid(nb - c) = 1 / (1 + 2^(cL - nbL))
                res[i] = frcp(1.0f + fexp2(r[rr + 1][i + 1] - r[rr + ri][i + ci]));
            }
            __builtin_nontemporal_store(res, reinterpret_cast<fx4*>(base + off + rr * NW));
        }
    }
}

extern "C" void kernel_launch(void* const* d_in, const int* in_sizes, int n_in,
                              void* d_out, int out_size, void* d_ws, size_t ws_size,
                              hipStream_t stream) {
    const float* img = (const float*)d_in[0];
    float* out = (float*)d_out;
    // 16 images * 128 work-ids/image = 2048 blocks of 256 threads
    lbp_kernel<<<2048, 256, 0, stream>>>(img, out);
}